// Round 4
// baseline (132.249 us; speedup 1.0000x reference)
//
#include <hip/hip_runtime.h>

#define WW 512
#define HH 512
#define CC 64
#define HW (HH*WW)
#define NSPLIT 8
#define CPS (CC/NSPLIT)

// 4-byte-aligned float2 / 8-byte-aligned float4 vector loads (gfx950 supports
// unaligned global access in HW; these emit single dwordx2/dwordx4).
typedef float f2v __attribute__((ext_vector_type(2), aligned(4)));
typedef float f4v __attribute__((ext_vector_type(4), aligned(8)));

__device__ __forceinline__ void invert3(const float* __restrict__ m, float* o) {
    float a = m[0], b = m[1], c = m[2];
    float d = m[3], e = m[4], f = m[5];
    float g = m[6], h = m[7], i = m[8];
    float C11 =  (e*i - f*h);
    float C12 = -(d*i - f*g);
    float C13 =  (d*h - e*g);
    float C21 = -(b*i - c*h);
    float C22 =  (a*i - c*g);
    float C23 = -(a*h - b*g);
    float C31 =  (b*f - c*e);
    float C32 = -(a*f - c*d);
    float C33 =  (a*e - b*d);
    float det = a*C11 + b*C12 + c*C13;
    float id = 1.0f / det;
    o[0] = C11*id; o[1] = C21*id; o[2] = C31*id;
    o[3] = C12*id; o[4] = C22*id; o[5] = C32*id;
    o[6] = C13*id; o[7] = C23*id; o[8] = C33*id;
}

__device__ __forceinline__ void reproj_pt(
    float px, float py, float d,
    const float Kinv[9],
    const float* __restrict__ cf, const float* __restrict__ ct,
    const float* __restrict__ Kt,
    float& ox, float& oy)
{
    float cx = Kinv[0]*px + Kinv[1]*py + Kinv[2];
    float cy = Kinv[3]*px + Kinv[4]*py + Kinv[5];
    float cz = Kinv[6]*px + Kinv[7]*py + Kinv[8];
    cx *= d; cy *= d; cz *= d;
    float wx = cf[0]*cx + cf[1]*cy + cf[2]*cz + cf[3];
    float wy = cf[4]*cx + cf[5]*cy + cf[6]*cz + cf[7];
    float wz = cf[8]*cx + cf[9]*cy + cf[10]*cz + cf[11];
    float qx = wx - ct[3], qy = wy - ct[7], qz = wz - ct[11];
    float ax = ct[0]*qx + ct[4]*qy + ct[8]*qz;
    float ay = ct[1]*qx + ct[5]*qy + ct[9]*qz;
    float az = ct[2]*qx + ct[6]*qy + ct[10]*qz;
    float p0 = Kt[0]*ax + Kt[1]*ay + Kt[2]*az;
    float p1 = Kt[3]*ax + Kt[4]*ay + Kt[5]*az;
    float p2 = Kt[6]*ax + Kt[7]*ay + Kt[8]*az;
    float zs = (fabsf(p2) > 1e-6f) ? p2 : 1e-6f;
    float u = p0 / zs;
    float v = p1 / zs;
    ox = u / 512.0f * 2.0f - 1.0f;
    oy = v / 512.0f * 2.0f - 1.0f;
}

// Bilinear state at sample (lx,ly): two row-pair offsets (pixel units) and
// 4 element weights matched to the loaded pairs (xc, xc+1) on rows y0,y0+1.
// OOB corners get zero element-weight; offsets are clamped in-range so the
// paired loads are always legal. Arithmetic for weights matches reference.
__device__ __forceinline__ void bilin_state(
    float lx, float ly, float4& ew, int& o0, int& o1)
{
    float xf = (lx + 1.0f) * 256.0f - 0.5f;
    float yf = (ly + 1.0f) * 256.0f - 0.5f;
    float x0 = floorf(xf), y0 = floorf(yf);
    float wx = xf - x0, wy = yf - y0;
    x0 = fminf(fmaxf(x0, -1e8f), 1e8f);
    y0 = fminf(fmaxf(y0, -1e8f), 1e8f);
    int x0i = (int)x0, y0i = (int)y0;

    float vx0 = (x0i >= 0 && x0i < WW) ? 1.0f : 0.0f;
    float vx1 = (x0i + 1 >= 0 && x0i + 1 < WW) ? 1.0f : 0.0f;
    float vy0 = (y0i >= 0 && y0i < HH) ? 1.0f : 0.0f;
    float vy1 = (y0i + 1 >= 0 && y0i + 1 < HH) ? 1.0f : 0.0f;
    float w00 = (1.0f - wx) * (1.0f - wy) * vx0 * vy0;
    float w10 = wx * (1.0f - wy) * vx1 * vy0;
    float w01 = (1.0f - wx) * wy * vx0 * vy1;
    float w11 = wx * wy * vx1 * vy1;

    int xc = min(max(x0i, 0), WW - 2);
    // element at xc / xc+1 takes the corner weight it coincides with
    float e0r0 = (xc == x0i) ? w00 : ((xc == x0i + 1) ? w10 : 0.0f);
    float e1r0 = (xc + 1 == x0i + 1) ? w10 : ((xc + 1 == x0i) ? w00 : 0.0f);
    float e0r1 = (xc == x0i) ? w01 : ((xc == x0i + 1) ? w11 : 0.0f);
    float e1r1 = (xc + 1 == x0i + 1) ? w11 : ((xc + 1 == x0i) ? w01 : 0.0f);
    ew = make_float4(e0r0, e1r0, e0r1, e1r1);
    o0 = min(max(y0i, 0), HH - 1) * WW + xc;
    o1 = min(max(y0i + 1, 0), HH - 1) * WW + xc;
}

// ---------- K1: reprojection fields l1_2, l2_1 (float2 per pixel) ----------
__global__ __launch_bounds__(256) void field_kernel(
    const float* __restrict__ d1p, const float* __restrict__ d2p,
    const float* __restrict__ K1, const float* __restrict__ K2,
    const float* __restrict__ cw1, const float* __restrict__ cw2,
    float2* __restrict__ l12f, float2* __restrict__ l21f)
{
    int pix = blockIdx.x * 256 + threadIdx.x;
    int j = pix & (WW - 1);
    int i = pix >> 9;
    float Ki1[9], Ki2[9];
    invert3(K1, Ki1);
    invert3(K2, Ki2);
    float px = j + 0.5f, py = i + 0.5f;
    float x, y;
    reproj_pt(px, py, d1p[pix], Ki1, cw1, cw2, K2, x, y);
    l12f[pix] = make_float2(x, y);
    reproj_pt(px, py, d2p[pix], Ki2, cw2, cw1, K1, x, y);
    l21f[pix] = make_float2(x, y);
}

// ---------- K2: packed bilinear state + cycle weight ----------
__global__ __launch_bounds__(256) void state_kernel(
    const float2* __restrict__ l12f, const float2* __restrict__ l21f,
    const float* __restrict__ m1p,
    float4* __restrict__ ewA4, float4* __restrict__ ewB4,
    int4* __restrict__ oAB4, float* __restrict__ wgtp)
{
    int pix = blockIdx.x * 256 + threadIdx.x;
    float2 l12 = l12f[pix];
    float2 l21 = l21f[pix];

    float4 ewA; int a0, a1;
    bilin_state(l12.x, l12.y, ewA, a0, a1);

    // bilinear sample of the l2_1 field at l1_2 (rows are 16B of float2 pairs)
    const float* FF = (const float*)l21f;
    f4v r0 = *(const f4v*)(FF + 2 * a0);
    f4v r1 = *(const f4v*)(FF + 2 * a1);
    float vx = ewA.x * r0.x + ewA.y * r0.z + ewA.z * r1.x + ewA.w * r1.z;
    float vy = ewA.x * r0.y + ewA.y * r0.w + ewA.z * r1.y + ewA.w * r1.w;

    int j = pix & (WW - 1);
    int i = pix >> 9;
    float gx = (j + 0.5f) / 512.0f * 2.0f - 1.0f;
    float gy = (i + 0.5f) / 512.0f * 2.0f - 1.0f;
    float ddx = gx - vx, ddy = gy - vy;
    float dist = sqrtf(ddx * ddx + ddy * ddy);
    float wgt = (dist < 0.0025f) ? m1p[pix] : 0.0f;

    float4 ewB; int b0, b1;
    bilin_state(l21.x, l21.y, ewB, b0, b1);

    ewA4[pix] = ewA;
    ewB4[pix] = ewB;
    oAB4[pix] = make_int4(a0, a1, b0, b1);
    wgtp[pix] = wgt;
}

// ---------- K3: pure gather loop, 8-way channel split ----------
__global__ __launch_bounds__(256) void gather_kernel(
    const float* __restrict__ f1, const float* __restrict__ f2,
    const float4* __restrict__ ewA4, const float4* __restrict__ ewB4,
    const int4* __restrict__ oAB4, const float* __restrict__ wgtp,
    float* __restrict__ out)
{
    int pix = blockIdx.x * 256 + threadIdx.x;
    float wgt = wgtp[pix];
    float lsum = 0.0f;

    if (wgt != 0.0f) {
        float4 ewA = ewA4[pix];
        float4 ewB = ewB4[pix];
        int4 o = oAB4[pix];
        const float* F1 = f1 + (size_t)blockIdx.y * CPS * HW;
        const float* F2 = f2 + (size_t)blockIdx.y * CPS * HW;
        float acc = 0.0f;
        #pragma unroll
        for (int c = 0; c < CPS; ++c) {
            f2v a0 = *(const f2v*)(F2 + o.x);   // f1_2 corners row y0
            f2v a1 = *(const f2v*)(F2 + o.y);   // row y0+1
            f2v b0 = *(const f2v*)(F1 + o.z);   // f2_1 corners row y0
            f2v b1 = *(const f2v*)(F1 + o.w);   // row y0+1
            float p1 = F1[pix];
            float p2 = F2[pix];
            float s1 = ewA.x * a0.x + ewA.y * a0.y + ewA.z * a1.x + ewA.w * a1.y;
            float s2 = ewB.x * b0.x + ewB.y * b0.y + ewB.z * b1.x + ewB.w * b1.y;
            float e1 = p1 - s1;
            float e2 = p2 - s2;
            acc += e1 * e1 + e2 * e2;
            F1 += HW;
            F2 += HW;
        }
        lsum = wgt * acc;
    }

    #pragma unroll
    for (int off = 32; off > 0; off >>= 1)
        lsum += __shfl_down(lsum, off);
    __shared__ float sred[4];
    int wave = threadIdx.x >> 6;
    if ((threadIdx.x & 63) == 0) sred[wave] = lsum;
    __syncthreads();
    if (threadIdx.x == 0) {
        float t = (sred[0] + sred[1]) + (sred[2] + sred[3]);
        atomicAdd(out, t * (1.0f / 262144.0f));
    }
}

// ---------- fallback: monolithic kernel (only if ws too small) ----------
__global__ __launch_bounds__(256) void mono_kernel(
    const float* __restrict__ f1, const float* __restrict__ f2,
    const float* __restrict__ d1p, const float* __restrict__ d2p,
    const float* __restrict__ m1p,
    const float* __restrict__ K1, const float* __restrict__ K2,
    const float* __restrict__ cw1, const float* __restrict__ cw2,
    float* __restrict__ out)
{
    int pix = blockIdx.x * 256 + threadIdx.x;
    int j = pix & (WW - 1);
    int i = pix >> 9;
    float Ki1[9], Ki2[9];
    invert3(K1, Ki1);
    invert3(K2, Ki2);
    float px = j + 0.5f, py = i + 0.5f;

    float l12x, l12y, l21x, l21y;
    reproj_pt(px, py, d1p[pix], Ki1, cw1, cw2, K2, l12x, l12y);
    reproj_pt(px, py, d2p[pix], Ki2, cw2, cw1, K1, l21x, l21y);

    float4 ewA; int a0, a1;
    bilin_state(l12x, l12y, ewA, a0, a1);

    float vx = 0.0f, vy = 0.0f;
    {   // recompute l2_1 at the 4 corner pixels
        int offs[2] = {a0, a1};
        #pragma unroll
        for (int r = 0; r < 2; ++r) {
            #pragma unroll
            for (int kx = 0; kx < 2; ++kx) {
                int off = offs[r] + kx;
                float w = (r == 0) ? (kx ? ewA.y : ewA.x) : (kx ? ewA.w : ewA.z);
                if (w != 0.0f) {
                    int cj = off & (WW - 1), ci = off >> 9;
                    float cxv, cyv;
                    reproj_pt(cj + 0.5f, ci + 0.5f, d2p[off], Ki2, cw2, cw1, K1, cxv, cyv);
                    vx += w * cxv;
                    vy += w * cyv;
                }
            }
        }
    }
    float gx = (j + 0.5f) / 512.0f * 2.0f - 1.0f;
    float gy = (i + 0.5f) / 512.0f * 2.0f - 1.0f;
    float ddx = gx - vx, ddy = gy - vy;
    float dist = sqrtf(ddx * ddx + ddy * ddy);
    float wgt = (dist < 0.0025f) ? m1p[pix] : 0.0f;

    float lsum = 0.0f;
    if (wgt != 0.0f) {
        float4 ewB; int b0, b1;
        bilin_state(l21x, l21y, ewB, b0, b1);
        float acc = 0.0f;
        const float* F1 = f1;
        const float* F2 = f2;
        for (int c = 0; c < CC; ++c) {
            f2v a0v = *(const f2v*)(F2 + a0);
            f2v a1v = *(const f2v*)(F2 + a1);
            f2v b0v = *(const f2v*)(F1 + b0);
            f2v b1v = *(const f2v*)(F1 + b1);
            float s1 = ewA.x * a0v.x + ewA.y * a0v.y + ewA.z * a1v.x + ewA.w * a1v.y;
            float s2 = ewB.x * b0v.x + ewB.y * b0v.y + ewB.z * b1v.x + ewB.w * b1v.y;
            float e1 = F1[pix] - s1;
            float e2 = F2[pix] - s2;
            acc += e1 * e1 + e2 * e2;
            F1 += HW; F2 += HW;
        }
        lsum = wgt * acc;
    }

    #pragma unroll
    for (int off = 32; off > 0; off >>= 1)
        lsum += __shfl_down(lsum, off);
    __shared__ float sred[4];
    if ((threadIdx.x & 63) == 0) sred[threadIdx.x >> 6] = lsum;
    __syncthreads();
    if (threadIdx.x == 0) {
        float t = (sred[0] + sred[1]) + (sred[2] + sred[3]);
        atomicAdd(out, t * (1.0f / 262144.0f));
    }
}

extern "C" void kernel_launch(void* const* d_in, const int* in_sizes, int n_in,
                              void* d_out, int out_size, void* d_ws, size_t ws_size,
                              hipStream_t stream) {
    const float* f1  = (const float*)d_in[0];
    const float* f2  = (const float*)d_in[1];
    const float* dp1 = (const float*)d_in[4];
    const float* dp2 = (const float*)d_in[5];
    const float* m1  = (const float*)d_in[6];
    const float* K1  = (const float*)d_in[8];
    const float* K2  = (const float*)d_in[9];
    const float* c1  = (const float*)d_in[10];
    const float* c2  = (const float*)d_in[11];

    float* out = (float*)d_out;
    hipMemsetAsync(out, 0, sizeof(float), stream);

    const size_t need = (size_t)HW * 68;  // 16+16+16 state, 8+8 fields, 4 wgt
    if (ws_size >= need) {
        char* ws = (char*)d_ws;
        float4* ewA4 = (float4*)(ws);
        float4* ewB4 = (float4*)(ws + (size_t)HW * 16);
        int4*   oAB4 = (int4*)(ws + (size_t)HW * 32);
        float2* l12f = (float2*)(ws + (size_t)HW * 48);
        float2* l21f = (float2*)(ws + (size_t)HW * 56);
        float*  wgtp = (float*)(ws + (size_t)HW * 64);

        field_kernel<<<HW / 256, 256, 0, stream>>>(
            dp1, dp2, K1, K2, c1, c2, l12f, l21f);
        state_kernel<<<HW / 256, 256, 0, stream>>>(
            l12f, l21f, m1, ewA4, ewB4, oAB4, wgtp);
        gather_kernel<<<dim3(HW / 256, NSPLIT), 256, 0, stream>>>(
            f1, f2, ewA4, ewB4, oAB4, wgtp, out);
    } else {
        mono_kernel<<<HW / 256, 256, 0, stream>>>(
            f1, f2, dp1, dp2, m1, K1, K2, c1, c2, out);
    }
}

// Round 5
// 81.750 us; speedup vs baseline: 1.6177x; 1.6177x over previous
//
#include <hip/hip_runtime.h>

#define WW 512
#define HH 512
#define CC 64
#define HW (HH*WW)
#define NSPLIT 4
#define CPS (CC/NSPLIT)

__device__ __forceinline__ void invert3(const float* __restrict__ m, float* o) {
    float a = m[0], b = m[1], c = m[2];
    float d = m[3], e = m[4], f = m[5];
    float g = m[6], h = m[7], i = m[8];
    float C11 =  (e*i - f*h);
    float C12 = -(d*i - f*g);
    float C13 =  (d*h - e*g);
    float C21 = -(b*i - c*h);
    float C22 =  (a*i - c*g);
    float C23 = -(a*h - b*g);
    float C31 =  (b*f - c*e);
    float C32 = -(a*f - c*d);
    float C33 =  (a*e - b*d);
    float det = a*C11 + b*C12 + c*C13;
    float id = 1.0f / det;
    o[0] = C11*id; o[1] = C21*id; o[2] = C31*id;
    o[3] = C12*id; o[4] = C22*id; o[5] = C32*id;
    o[6] = C13*id; o[7] = C23*id; o[8] = C33*id;
}

__device__ __forceinline__ void reproj_pt(
    float px, float py, float d,
    const float Kinv[9],
    const float* __restrict__ cf, const float* __restrict__ ct,
    const float* __restrict__ Kt,
    float& ox, float& oy)
{
    float cx = Kinv[0]*px + Kinv[1]*py + Kinv[2];
    float cy = Kinv[3]*px + Kinv[4]*py + Kinv[5];
    float cz = Kinv[6]*px + Kinv[7]*py + Kinv[8];
    cx *= d; cy *= d; cz *= d;
    float wx = cf[0]*cx + cf[1]*cy + cf[2]*cz + cf[3];
    float wy = cf[4]*cx + cf[5]*cy + cf[6]*cz + cf[7];
    float wz = cf[8]*cx + cf[9]*cy + cf[10]*cz + cf[11];
    float qx = wx - ct[3], qy = wy - ct[7], qz = wz - ct[11];
    float ax = ct[0]*qx + ct[4]*qy + ct[8]*qz;
    float ay = ct[1]*qx + ct[5]*qy + ct[9]*qz;
    float az = ct[2]*qx + ct[6]*qy + ct[10]*qz;
    float p0 = Kt[0]*ax + Kt[1]*ay + Kt[2]*az;
    float p1 = Kt[3]*ax + Kt[4]*ay + Kt[5]*az;
    float p2 = Kt[6]*ax + Kt[7]*ay + Kt[8]*az;
    float zs = (fabsf(p2) > 1e-6f) ? p2 : 1e-6f;
    float u = p0 / zs;
    float v = p1 / zs;
    ox = u / 512.0f * 2.0f - 1.0f;
    oy = v / 512.0f * 2.0f - 1.0f;
}

// Bilinear state at (lx,ly): two row offsets (clamped in-range) and 4
// element-weights matched to elements (xc, xc+1) on rows y0,y0+1. OOB
// corners carry zero weight (verified bit-equal to reference in R4).
__device__ __forceinline__ void bilin_state(
    float lx, float ly, float4& ew, int& o0, int& o1)
{
    float xf = (lx + 1.0f) * 256.0f - 0.5f;
    float yf = (ly + 1.0f) * 256.0f - 0.5f;
    float x0 = floorf(xf), y0 = floorf(yf);
    float wx = xf - x0, wy = yf - y0;
    x0 = fminf(fmaxf(x0, -1e8f), 1e8f);
    y0 = fminf(fmaxf(y0, -1e8f), 1e8f);
    int x0i = (int)x0, y0i = (int)y0;

    float vx0 = (x0i >= 0 && x0i < WW) ? 1.0f : 0.0f;
    float vx1 = (x0i + 1 >= 0 && x0i + 1 < WW) ? 1.0f : 0.0f;
    float vy0 = (y0i >= 0 && y0i < HH) ? 1.0f : 0.0f;
    float vy1 = (y0i + 1 >= 0 && y0i + 1 < HH) ? 1.0f : 0.0f;
    float w00 = (1.0f - wx) * (1.0f - wy) * vx0 * vy0;
    float w10 = wx * (1.0f - wy) * vx1 * vy0;
    float w01 = (1.0f - wx) * wy * vx0 * vy1;
    float w11 = wx * wy * vx1 * vy1;

    int xc = min(max(x0i, 0), WW - 2);
    float e0r0 = (xc == x0i) ? w00 : ((xc == x0i + 1) ? w10 : 0.0f);
    float e1r0 = (xc + 1 == x0i + 1) ? w10 : ((xc + 1 == x0i) ? w00 : 0.0f);
    float e0r1 = (xc == x0i) ? w01 : ((xc == x0i + 1) ? w11 : 0.0f);
    float e1r1 = (xc + 1 == x0i + 1) ? w11 : ((xc + 1 == x0i) ? w01 : 0.0f);
    ew = make_float4(e0r0, e1r0, e0r1, e1r1);
    o0 = min(max(y0i, 0), HH - 1) * WW + xc;
    o1 = min(max(y0i + 1, 0), HH - 1) * WW + xc;
}

// ---------- K1: merged per-pixel setup -> 52B packed state ----------
__global__ __launch_bounds__(256) void setup_kernel(
    const float* __restrict__ d1p, const float* __restrict__ d2p,
    const float* __restrict__ m1p,
    const float* __restrict__ K1, const float* __restrict__ K2,
    const float* __restrict__ cw1, const float* __restrict__ cw2,
    float4* __restrict__ ewA4, float4* __restrict__ ewB4,
    int4* __restrict__ oAB4, float* __restrict__ wgtp,
    float* __restrict__ out)
{
    int pix = blockIdx.x * 256 + threadIdx.x;
    if (pix == 0) *out = 0.0f;   // replaces hipMemsetAsync (gather runs after)
    int j = pix & (WW - 1);
    int i = pix >> 9;
    float Ki1[9], Ki2[9];
    invert3(K1, Ki1);
    invert3(K2, Ki2);
    float px = j + 0.5f, py = i + 0.5f;

    float l12x, l12y, l21x, l21y;
    reproj_pt(px, py, d1p[pix], Ki1, cw1, cw2, K2, l12x, l12y);
    reproj_pt(px, py, d2p[pix], Ki2, cw2, cw1, K1, l21x, l21y);

    float4 ewA; int a0, a1;
    bilin_state(l12x, l12y, ewA, a0, a1);

    // l1_2_1 = bilinear sample of the l2_1 field at l1_2, by recomputing
    // l2_1 at the 4 corner pixels (exact: field at integer pixel is the
    // reprojection of that pixel with its depth).
    float vx = 0.0f, vy = 0.0f;
    {
        int offs[2] = {a0, a1};
        #pragma unroll
        for (int r = 0; r < 2; ++r) {
            #pragma unroll
            for (int kx = 0; kx < 2; ++kx) {
                int off = offs[r] + kx;
                float w = (r == 0) ? (kx ? ewA.y : ewA.x) : (kx ? ewA.w : ewA.z);
                if (w != 0.0f) {
                    int cj = off & (WW - 1), ci = off >> 9;
                    float cxv, cyv;
                    reproj_pt(cj + 0.5f, ci + 0.5f, d2p[off], Ki2, cw2, cw1, K1, cxv, cyv);
                    vx += w * cxv;
                    vy += w * cyv;
                }
            }
        }
    }
    float gx = (j + 0.5f) / 512.0f * 2.0f - 1.0f;
    float gy = (i + 0.5f) / 512.0f * 2.0f - 1.0f;
    float ddx = gx - vx, ddy = gy - vy;
    float dist = sqrtf(ddx * ddx + ddy * ddy);
    float wgt = (dist < 0.0025f) ? m1p[pix] : 0.0f;

    float4 ewB; int b0, b1;
    bilin_state(l21x, l21y, ewB, b0, b1);

    ewA4[pix] = ewA;
    ewB4[pix] = ewB;
    oAB4[pix] = make_int4(a0, a1, b0, b1);
    wgtp[pix] = wgt;
}

// ---------- K2: pure gather, 4-way channel split, 4-channel load batches ----------
__global__ __launch_bounds__(256) void gather_kernel(
    const float* __restrict__ f1, const float* __restrict__ f2,
    const float4* __restrict__ ewA4, const float4* __restrict__ ewB4,
    const int4* __restrict__ oAB4, const float* __restrict__ wgtp,
    float* __restrict__ out)
{
    int pix = blockIdx.x * 256 + threadIdx.x;
    float wgt = wgtp[pix];
    float lsum = 0.0f;

    if (wgt != 0.0f) {
        float4 ewA = ewA4[pix];
        float4 ewB = ewB4[pix];
        int4 o = oAB4[pix];
        const float* F1 = f1 + (size_t)blockIdx.y * CPS * HW;
        const float* F2 = f2 + (size_t)blockIdx.y * CPS * HW;
        float acc = 0.0f;
        #pragma unroll
        for (int c = 0; c < CPS; c += 4) {
            // batch all 40 loads of 4 channel planes before consuming
            float r[4][10];
            #pragma unroll
            for (int u = 0; u < 4; ++u) {
                const float* G1 = F1 + (size_t)u * HW;
                const float* G2 = F2 + (size_t)u * HW;
                r[u][0] = G2[o.x];     r[u][1] = G2[o.x + 1];
                r[u][2] = G2[o.y];     r[u][3] = G2[o.y + 1];
                r[u][4] = G1[o.z];     r[u][5] = G1[o.z + 1];
                r[u][6] = G1[o.w];     r[u][7] = G1[o.w + 1];
                r[u][8] = G1[pix];     r[u][9] = G2[pix];
            }
            #pragma unroll
            for (int u = 0; u < 4; ++u) {
                float s1 = ewA.x*r[u][0] + ewA.y*r[u][1] + ewA.z*r[u][2] + ewA.w*r[u][3];
                float s2 = ewB.x*r[u][4] + ewB.y*r[u][5] + ewB.z*r[u][6] + ewB.w*r[u][7];
                float e1 = r[u][8] - s1;
                float e2 = r[u][9] - s2;
                acc += e1 * e1 + e2 * e2;
            }
            F1 += 4 * HW;
            F2 += 4 * HW;
        }
        lsum = wgt * acc;
    }

    #pragma unroll
    for (int off = 32; off > 0; off >>= 1)
        lsum += __shfl_down(lsum, off);
    __shared__ float sred[4];
    int wave = threadIdx.x >> 6;
    if ((threadIdx.x & 63) == 0) sred[wave] = lsum;
    __syncthreads();
    if (threadIdx.x == 0) {
        float t = (sred[0] + sred[1]) + (sred[2] + sred[3]);
        atomicAdd(out, t * (1.0f / 262144.0f));
    }
}

// ---------- fallback: monolithic kernel (only if ws too small) ----------
__global__ __launch_bounds__(256) void mono_kernel(
    const float* __restrict__ f1, const float* __restrict__ f2,
    const float* __restrict__ d1p, const float* __restrict__ d2p,
    const float* __restrict__ m1p,
    const float* __restrict__ K1, const float* __restrict__ K2,
    const float* __restrict__ cw1, const float* __restrict__ cw2,
    float* __restrict__ out)
{
    int pix = blockIdx.x * 256 + threadIdx.x;
    int j = pix & (WW - 1);
    int i = pix >> 9;
    float Ki1[9], Ki2[9];
    invert3(K1, Ki1);
    invert3(K2, Ki2);
    float px = j + 0.5f, py = i + 0.5f;

    float l12x, l12y, l21x, l21y;
    reproj_pt(px, py, d1p[pix], Ki1, cw1, cw2, K2, l12x, l12y);
    reproj_pt(px, py, d2p[pix], Ki2, cw2, cw1, K1, l21x, l21y);

    float4 ewA; int a0, a1;
    bilin_state(l12x, l12y, ewA, a0, a1);

    float vx = 0.0f, vy = 0.0f;
    {
        int offs[2] = {a0, a1};
        #pragma unroll
        for (int r = 0; r < 2; ++r) {
            #pragma unroll
            for (int kx = 0; kx < 2; ++kx) {
                int off = offs[r] + kx;
                float w = (r == 0) ? (kx ? ewA.y : ewA.x) : (kx ? ewA.w : ewA.z);
                if (w != 0.0f) {
                    int cj = off & (WW - 1), ci = off >> 9;
                    float cxv, cyv;
                    reproj_pt(cj + 0.5f, ci + 0.5f, d2p[off], Ki2, cw2, cw1, K1, cxv, cyv);
                    vx += w * cxv;
                    vy += w * cyv;
                }
            }
        }
    }
    float gx = (j + 0.5f) / 512.0f * 2.0f - 1.0f;
    float gy = (i + 0.5f) / 512.0f * 2.0f - 1.0f;
    float ddx = gx - vx, ddy = gy - vy;
    float dist = sqrtf(ddx * ddx + ddy * ddy);
    float wgt = (dist < 0.0025f) ? m1p[pix] : 0.0f;

    float lsum = 0.0f;
    if (wgt != 0.0f) {
        float4 ewB; int b0, b1;
        bilin_state(l21x, l21y, ewB, b0, b1);
        float acc = 0.0f;
        const float* F1 = f1;
        const float* F2 = f2;
        for (int c = 0; c < CC; ++c) {
            float s1 = ewA.x*F2[a0] + ewA.y*F2[a0+1] + ewA.z*F2[a1] + ewA.w*F2[a1+1];
            float s2 = ewB.x*F1[b0] + ewB.y*F1[b0+1] + ewB.z*F1[b1] + ewB.w*F1[b1+1];
            float e1 = F1[pix] - s1;
            float e2 = F2[pix] - s2;
            acc += e1 * e1 + e2 * e2;
            F1 += HW; F2 += HW;
        }
        lsum = wgt * acc;
    }

    #pragma unroll
    for (int off = 32; off > 0; off >>= 1)
        lsum += __shfl_down(lsum, off);
    __shared__ float sred[4];
    if ((threadIdx.x & 63) == 0) sred[threadIdx.x >> 6] = lsum;
    __syncthreads();
    if (threadIdx.x == 0) {
        float t = (sred[0] + sred[1]) + (sred[2] + sred[3]);
        atomicAdd(out, t * (1.0f / 262144.0f));
    }
}

extern "C" void kernel_launch(void* const* d_in, const int* in_sizes, int n_in,
                              void* d_out, int out_size, void* d_ws, size_t ws_size,
                              hipStream_t stream) {
    const float* f1  = (const float*)d_in[0];
    const float* f2  = (const float*)d_in[1];
    const float* dp1 = (const float*)d_in[4];
    const float* dp2 = (const float*)d_in[5];
    const float* m1  = (const float*)d_in[6];
    const float* K1  = (const float*)d_in[8];
    const float* K2  = (const float*)d_in[9];
    const float* c1  = (const float*)d_in[10];
    const float* c2  = (const float*)d_in[11];

    float* out = (float*)d_out;

    const size_t need = (size_t)HW * 52;  // ewA(16)+ewB(16)+oAB(16)+wgt(4)
    if (ws_size >= need) {
        char* ws = (char*)d_ws;
        float4* ewA4 = (float4*)(ws);
        float4* ewB4 = (float4*)(ws + (size_t)HW * 16);
        int4*   oAB4 = (int4*)(ws + (size_t)HW * 32);
        float*  wgtp = (float*)(ws + (size_t)HW * 48);

        setup_kernel<<<HW / 256, 256, 0, stream>>>(
            dp1, dp2, m1, K1, K2, c1, c2, ewA4, ewB4, oAB4, wgtp, out);
        gather_kernel<<<dim3(HW / 256, NSPLIT), 256, 0, stream>>>(
            f1, f2, ewA4, ewB4, oAB4, wgtp, out);
    } else {
        hipMemsetAsync(out, 0, sizeof(float), stream);
        mono_kernel<<<HW / 256, 256, 0, stream>>>(
            f1, f2, dp1, dp2, m1, K1, K2, c1, c2, out);
    }
}